// Round 1
// baseline (814.078 us; speedup 1.0000x reference)
//
#include <hip/hip_runtime.h>
#include <math.h>

// ---------------------------------------------------------------------------
// GCN: h1 = relu(Agg(x) @ W1 + b1); h2 = relu(Agg(h1) @ W2 + b2);
//      g = mean-pool(h2, batch); out = relu(g@fc1+b)@fc2+b
// Agg(v)[n] = sum_{e: dst=n} v[src]*norm_e + v[n]*dinv[n]^2,
// norm_e = dinv[src]*dinv[dst], dinv = 1/sqrt(deg+1)  (self-loop included)
// Key: aggregate BEFORE the linear transform (they commute) -> gather 4/64
// channels instead of 64/128.
// ---------------------------------------------------------------------------

__global__ void k_count_deg(const int* __restrict__ dst, int E, int* __restrict__ deg) {
  int i = blockIdx.x * blockDim.x + threadIdx.x;
  if (i < E) atomicAdd(&deg[dst[i]], 1);
}

__global__ void k_dinv(const int* __restrict__ deg, float* __restrict__ dinv, int N) {
  int i = blockIdx.x * blockDim.x + threadIdx.x;
  if (i < N) dinv[i] = 1.0f / sqrtf((float)(deg[i] + 1));  // +1 = self loop; always > 0
}

// Single-block exclusive scan of deg -> row_ptr[N+1]; also seeds cursor.
__global__ void k_scan(const int* __restrict__ deg, int* __restrict__ row_ptr,
                       int* __restrict__ cursor, int N) {
  __shared__ int sums[1024];
  int t = threadIdx.x;
  int chunk = (N + 1023) >> 10;
  int beg = t * chunk;
  int end = min(beg + chunk, N);
  int s = 0;
  for (int i = beg; i < end; ++i) s += deg[i];
  sums[t] = s;
  __syncthreads();
  for (int o = 1; o < 1024; o <<= 1) {
    int v = (t >= o) ? sums[t - o] : 0;
    __syncthreads();
    sums[t] += v;
    __syncthreads();
  }
  int run = sums[t] - s;  // exclusive prefix
  for (int i = beg; i < end; ++i) {
    row_ptr[i] = run;
    cursor[i] = run;
    run += deg[i];
  }
  if (t == 1023) row_ptr[N] = sums[1023];
}

__global__ void k_fill(const int* __restrict__ src, const int* __restrict__ dst, int E,
                       const float* __restrict__ dinv, int* __restrict__ cursor,
                       int* __restrict__ csr_src, float* __restrict__ csr_norm) {
  int i = blockIdx.x * blockDim.x + threadIdx.x;
  if (i < E) {
    int s = src[i], d = dst[i];
    int pos = atomicAdd(&cursor[d], 1);
    csr_src[pos] = s;
    csr_norm[pos] = dinv[s] * dinv[d];
  }
}

// conv1: wave per node; lanes parallel over edges (gather float4), butterfly
// reduce, then lane = output channel for the 4x64 transform.
__global__ void k_conv1(const float* __restrict__ x, const int* __restrict__ row_ptr,
                        const int* __restrict__ csr_src, const float* __restrict__ csr_norm,
                        const float* __restrict__ dinv, const float* __restrict__ W1,
                        const float* __restrict__ b1, float* __restrict__ h1, int N) {
  int lane = threadIdx.x & 63;
  int wid = (blockIdx.x * blockDim.x + threadIdx.x) >> 6;
  int nw = (gridDim.x * blockDim.x) >> 6;
  const float4* x4 = (const float4*)x;
  for (int n = wid; n < N; n += nw) {
    int e0 = row_ptr[n], e1 = row_ptr[n + 1];
    float ax = 0.f, ay = 0.f, az = 0.f, aw = 0.f;
    for (int j = e0 + lane; j < e1; j += 64) {
      int s = csr_src[j];
      float nm = csr_norm[j];
      float4 xs = x4[s];
      ax = fmaf(xs.x, nm, ax); ay = fmaf(xs.y, nm, ay);
      az = fmaf(xs.z, nm, az); aw = fmaf(xs.w, nm, aw);
    }
#pragma unroll
    for (int o = 32; o; o >>= 1) {
      ax += __shfl_xor(ax, o); ay += __shfl_xor(ay, o);
      az += __shfl_xor(az, o); aw += __shfl_xor(aw, o);
    }
    float di = dinv[n];
    float sn = di * di;
    float4 xn = x4[n];
    ax = fmaf(xn.x, sn, ax); ay = fmaf(xn.y, sn, ay);
    az = fmaf(xn.z, sn, az); aw = fmaf(xn.w, sn, aw);
    float o0 = b1[lane];
    o0 = fmaf(ax, W1[lane], o0);
    o0 = fmaf(ay, W1[64 + lane], o0);
    o0 = fmaf(az, W1[128 + lane], o0);
    o0 = fmaf(aw, W1[192 + lane], o0);
    h1[(size_t)n * 64 + lane] = fmaxf(o0, 0.f);
  }
}

// conv2: wave per node; lane = input channel (64). Sequential edge loop with
// coalesced 256B gathers of h1 rows; then 64->128 transform via __shfl
// broadcast + W2 in LDS.
__global__ void k_conv2(const float* __restrict__ h1, const int* __restrict__ row_ptr,
                        const int* __restrict__ csr_src, const float* __restrict__ csr_norm,
                        const float* __restrict__ dinv, const float* __restrict__ W2,
                        const float* __restrict__ b2, float* __restrict__ h2, int N) {
  __shared__ float W2s[64 * 128];
  for (int i = threadIdx.x; i < 64 * 128; i += blockDim.x) W2s[i] = W2[i];
  __syncthreads();
  int lane = threadIdx.x & 63;
  int wid = (blockIdx.x * blockDim.x + threadIdx.x) >> 6;
  int nw = (gridDim.x * blockDim.x) >> 6;
  for (int n = wid; n < N; n += nw) {
    int e0 = row_ptr[n], e1 = row_ptr[n + 1];
    float acc = 0.f;
    for (int j = e0; j < e1; ++j) {
      int s = csr_src[j];
      float nm = csr_norm[j];
      acc = fmaf(h1[(size_t)s * 64 + lane], nm, acc);
    }
    float di = dinv[n];
    acc = fmaf(h1[(size_t)n * 64 + lane], di * di, acc);
    float o0 = b2[lane], o1 = b2[64 + lane];
#pragma unroll 8
    for (int k = 0; k < 64; ++k) {
      float v = __shfl(acc, k);
      o0 = fmaf(v, W2s[k * 128 + lane], o0);
      o1 = fmaf(v, W2s[k * 128 + 64 + lane], o1);
    }
    h2[(size_t)n * 128 + lane] = fmaxf(o0, 0.f);
    h2[(size_t)n * 128 + 64 + lane] = fmaxf(o1, 0.f);
  }
}

__device__ __forceinline__ int lower_bound(const int* __restrict__ a, int n, int key) {
  int lo = 0, hi = n;
  while (lo < hi) {
    int m = (lo + hi) >> 1;
    if (a[m] < key) lo = m + 1; else hi = m;
  }
  return lo;
}

// block per graph: mean-pool h2 over [start,end), then fc1(relu)+fc2 on wave 0.
__global__ void k_pool_fc(const float* __restrict__ h2, const int* __restrict__ batch,
                          const float* __restrict__ fc1W, const float* __restrict__ fc1b,
                          const float* __restrict__ fc2W, const float* __restrict__ fc2b,
                          float* __restrict__ out, int N, int G) {
  int g = blockIdx.x;
  __shared__ int bounds[2];
  if (threadIdx.x == 0) bounds[0] = lower_bound(batch, N, g);
  if (threadIdx.x == 1) bounds[1] = lower_bound(batch, N, g + 1);
  __syncthreads();
  int beg = bounds[0], end = bounds[1];
  int c = threadIdx.x & 127;
  int gr = threadIdx.x >> 7;  // 2 node-stride groups
  float acc = 0.f;
  for (int i = beg + gr; i < end; i += 2) acc += h2[(size_t)i * 128 + c];
  __shared__ float red[256];
  __shared__ float grow[128];
  red[threadIdx.x] = acc;
  __syncthreads();
  if (threadIdx.x < 128) {
    float s = red[threadIdx.x] + red[threadIdx.x + 128];
    int cnt = end - beg;
    grow[threadIdx.x] = s / (float)max(cnt, 1);
  }
  __syncthreads();
  if (threadIdx.x < 64) {
    int c1 = threadIdx.x;
    float o = fc1b[c1];
#pragma unroll 8
    for (int k = 0; k < 128; ++k) o = fmaf(grow[k], fc1W[k * 64 + c1], o);
    o = fmaxf(o, 0.f);
    float v = o * fc2W[c1];
#pragma unroll
    for (int off = 32; off; off >>= 1) v += __shfl_xor(v, off);
    if (c1 == 0) out[g] = v + fc2b[0];
  }
}

extern "C" void kernel_launch(void* const* d_in, const int* in_sizes, int n_in,
                              void* d_out, int out_size, void* d_ws, size_t ws_size,
                              hipStream_t stream) {
  const float* x = (const float*)d_in[0];
  const int* ei = (const int*)d_in[1];
  const int* batch = (const int*)d_in[2];
  const float* W1 = (const float*)d_in[3];
  const float* b1 = (const float*)d_in[4];
  const float* W2 = (const float*)d_in[5];
  const float* b2 = (const float*)d_in[6];
  const float* fc1W = (const float*)d_in[7];
  const float* fc1b = (const float*)d_in[8];
  const float* fc2W = (const float*)d_in[9];
  const float* fc2b = (const float*)d_in[10];
  float* out = (float*)d_out;

  int N = in_sizes[0] / 4;   // 100000
  int E = in_sizes[1] / 2;   // 1600000
  int G = out_size;          // 1024
  const int* src = ei;
  const int* dst = ei + E;

  char* ws = (char*)d_ws;
  size_t off = 0;
  auto take = [&](size_t b) {
    char* p = ws + off;
    off += (b + 255) & ~(size_t)255;
    return p;
  };
  int* deg      = (int*)take((size_t)N * 4);
  int* row_ptr  = (int*)take((size_t)(N + 1) * 4);
  int* cursor   = (int*)take((size_t)N * 4);
  float* dinv   = (float*)take((size_t)N * 4);
  int* csr_src  = (int*)take((size_t)E * 4);
  float* csr_nm = (float*)take((size_t)E * 4);
  float* h1     = (float*)take((size_t)N * 64 * 4);
  float* h2     = (float*)take((size_t)N * 128 * 4);
  (void)ws_size;

  hipMemsetAsync(deg, 0, (size_t)N * 4, stream);
  k_count_deg<<<(E + 255) / 256, 256, 0, stream>>>(dst, E, deg);
  k_dinv<<<(N + 255) / 256, 256, 0, stream>>>(deg, dinv, N);
  k_scan<<<1, 1024, 0, stream>>>(deg, row_ptr, cursor, N);
  k_fill<<<(E + 255) / 256, 256, 0, stream>>>(src, dst, E, dinv, cursor, csr_src, csr_nm);
  k_conv1<<<4096, 256, 0, stream>>>(x, row_ptr, csr_src, csr_nm, dinv, W1, b1, h1, N);
  k_conv2<<<2048, 256, 0, stream>>>(h1, row_ptr, csr_src, csr_nm, dinv, W2, b2, h2, N);
  k_pool_fc<<<G, 256, 0, stream>>>(h2, batch, fc1W, fc1b, fc2W, fc2b, out, N, G);
}

// Round 2
// 473.257 us; speedup vs baseline: 1.7202x; 1.7202x over previous
//
#include <hip/hip_runtime.h>
#include <math.h>

// ---------------------------------------------------------------------------
// GCN: h1 = relu(Agg(x) @ W1 + b1); h2 = relu(Agg(h1) @ W2 + b2);
//      g = mean-pool(h2, batch); out = relu(g@fc1+b)@fc2+b
// Agg(v)[n] = dinv[n] * ( sum_{e: dst=n} v'[src] + v'[n] ),  v' = v * dinv
// (norm_e = dinv[src]*dinv[dst] factors into pre/post scaling -> CSR stores
//  src only, no per-edge norm.)
// ---------------------------------------------------------------------------

#define SCB 1024  // scan elements per block

__global__ void k_count_deg(const int* __restrict__ dst, int E, int* __restrict__ deg) {
  int i = blockIdx.x * blockDim.x + threadIdx.x;
  if (i < E) atomicAdd(&deg[dst[i]], 1);
}

// dinv + pre-scaled features x' = x * dinv
__global__ void k_prep(const int* __restrict__ deg, const float* __restrict__ x,
                       float* __restrict__ dinv, float* __restrict__ xp, int N) {
  int i = blockIdx.x * blockDim.x + threadIdx.x;
  if (i < N) {
    float di = 1.0f / sqrtf((float)(deg[i] + 1));  // +1 self loop; always > 0
    dinv[i] = di;
    float4 v = ((const float4*)x)[i];
    v.x *= di; v.y *= di; v.z *= di; v.w *= di;
    ((float4*)xp)[i] = v;
  }
}

// --- 3-phase exclusive scan of deg -> row_ptr[N+1], cursor seeded ---
__global__ void k_bsum(const int* __restrict__ deg, int* __restrict__ bsum, int N) {
  int b = blockIdx.x, t = threadIdx.x;
  int base = b * SCB;
  int s = 0;
  for (int i = t; i < SCB; i += 256) {
    int idx = base + i;
    if (idx < N) s += deg[idx];
  }
#pragma unroll
  for (int o = 32; o; o >>= 1) s += __shfl_xor(s, o);
  __shared__ int ws[4];
  if ((t & 63) == 0) ws[t >> 6] = s;
  __syncthreads();
  if (t == 0) bsum[b] = ws[0] + ws[1] + ws[2] + ws[3];
}

__global__ void k_scan_b(int* __restrict__ bsum, int nb) {  // 1 block; bsum[nb] <- total
  __shared__ int sh[1024];
  int t = threadIdx.x;
  int v = (t < nb) ? bsum[t] : 0;
  sh[t] = v;
  __syncthreads();
  for (int o = 1; o < 1024; o <<= 1) {
    int u = (t >= o) ? sh[t - o] : 0;
    __syncthreads();
    sh[t] += u;
    __syncthreads();
  }
  if (t < nb) bsum[t] = sh[t] - v;  // exclusive
  if (t == 1023) bsum[nb] = sh[1023];
}

__global__ void k_rowptr(const int* __restrict__ deg, const int* __restrict__ bsum,
                         int* __restrict__ row_ptr, int* __restrict__ cursor, int N) {
  int b = blockIdx.x, t = threadIdx.x;
  int base = b * SCB + t * 4;
  int d0 = 0, d1 = 0, d2 = 0, d3 = 0;
  if (base + 0 < N) d0 = deg[base + 0];
  if (base + 1 < N) d1 = deg[base + 1];
  if (base + 2 < N) d2 = deg[base + 2];
  if (base + 3 < N) d3 = deg[base + 3];
  int s = d0 + d1 + d2 + d3;
  __shared__ int sh[256];
  sh[t] = s;
  __syncthreads();
  for (int o = 1; o < 256; o <<= 1) {
    int u = (t >= o) ? sh[t - o] : 0;
    __syncthreads();
    sh[t] += u;
    __syncthreads();
  }
  int run = bsum[b] + sh[t] - s;
  if (base + 0 < N) { row_ptr[base + 0] = run; cursor[base + 0] = run; run += d0; }
  if (base + 1 < N) { row_ptr[base + 1] = run; cursor[base + 1] = run; run += d1; }
  if (base + 2 < N) { row_ptr[base + 2] = run; cursor[base + 2] = run; run += d2; }
  if (base + 3 < N) { row_ptr[base + 3] = run; cursor[base + 3] = run; run += d3; }
  if (b == 0 && t == 0) row_ptr[N] = bsum[gridDim.x];  // total
}

__global__ void k_fill(const int* __restrict__ src, const int* __restrict__ dst, int E,
                       int* __restrict__ cursor, int* __restrict__ csr_src) {
  int i = blockIdx.x * blockDim.x + threadIdx.x;
  if (i < E) {
    int d = dst[i];
    int pos = atomicAdd(&cursor[d], 1);
    csr_src[pos] = src[i];
  }
}

// conv1: wave per node; lanes parallel over edges (gather float4 of xp),
// butterfly reduce, then lane = output channel for the 4x64 transform.
// Writes h1' = relu(h1) * dinv[n] (pre-scaled for conv2).
__global__ void k_conv1(const float* __restrict__ xp, const int* __restrict__ row_ptr,
                        const int* __restrict__ csr_src, const float* __restrict__ dinv,
                        const float* __restrict__ W1, const float* __restrict__ b1,
                        float* __restrict__ h1p, int N) {
  int lane = threadIdx.x & 63;
  int wid = (blockIdx.x * blockDim.x + threadIdx.x) >> 6;
  int nw = (gridDim.x * blockDim.x) >> 6;
  const float4* x4 = (const float4*)xp;
  for (int n = wid; n < N; n += nw) {
    int e0 = row_ptr[n], e1 = row_ptr[n + 1];
    float ax = 0.f, ay = 0.f, az = 0.f, aw = 0.f;
    for (int j = e0 + lane; j < e1; j += 64) {
      float4 xs = x4[csr_src[j]];
      ax += xs.x; ay += xs.y; az += xs.z; aw += xs.w;
    }
#pragma unroll
    for (int o = 32; o; o >>= 1) {
      ax += __shfl_xor(ax, o); ay += __shfl_xor(ay, o);
      az += __shfl_xor(az, o); aw += __shfl_xor(aw, o);
    }
    float di = dinv[n];
    float4 xn = x4[n];
    ax = (ax + xn.x) * di; ay = (ay + xn.y) * di;
    az = (az + xn.z) * di; aw = (aw + xn.w) * di;
    float o0 = b1[lane];
    o0 = fmaf(ax, W1[lane], o0);
    o0 = fmaf(ay, W1[64 + lane], o0);
    o0 = fmaf(az, W1[128 + lane], o0);
    o0 = fmaf(aw, W1[192 + lane], o0);
    h1p[(size_t)n * 64 + lane] = fmaxf(o0, 0.f) * di;
  }
}

// conv2: wave per node; lane = input channel (64). Edge loop unrolled x4 with
// 4 accumulators (4 gathers in flight); 64->128 transform via __shfl + W2 LDS.
__global__ void __launch_bounds__(512) k_conv2(
    const float* __restrict__ h1p, const int* __restrict__ row_ptr,
    const int* __restrict__ csr_src, const float* __restrict__ dinv,
    const float* __restrict__ W2, const float* __restrict__ b2,
    float* __restrict__ h2, int N) {
  __shared__ float W2s[64 * 128];
  for (int i = threadIdx.x; i < 64 * 128; i += blockDim.x) W2s[i] = W2[i];
  __syncthreads();
  int lane = threadIdx.x & 63;
  int wid = (blockIdx.x * blockDim.x + threadIdx.x) >> 6;
  int nw = (gridDim.x * blockDim.x) >> 6;
  for (int n = wid; n < N; n += nw) {
    int e0 = row_ptr[n], e1 = row_ptr[n + 1];
    float a0 = 0.f, a1 = 0.f, a2 = 0.f, a3 = 0.f;
    int j = e0;
    for (; j + 4 <= e1; j += 4) {
      int s0 = csr_src[j], s1 = csr_src[j + 1], s2 = csr_src[j + 2], s3 = csr_src[j + 3];
      a0 += h1p[(size_t)s0 * 64 + lane];
      a1 += h1p[(size_t)s1 * 64 + lane];
      a2 += h1p[(size_t)s2 * 64 + lane];
      a3 += h1p[(size_t)s3 * 64 + lane];
    }
    for (; j < e1; ++j) a0 += h1p[(size_t)csr_src[j] * 64 + lane];
    float acc = (a0 + a1) + (a2 + a3);
    acc += h1p[(size_t)n * 64 + lane];  // self loop (pre-scaled)
    acc *= dinv[n];
    float o0 = b2[lane], o1 = b2[64 + lane];
#pragma unroll 8
    for (int k = 0; k < 64; ++k) {
      float v = __shfl(acc, k);
      o0 = fmaf(v, W2s[k * 128 + lane], o0);
      o1 = fmaf(v, W2s[k * 128 + 64 + lane], o1);
    }
    h2[(size_t)n * 128 + lane] = fmaxf(o0, 0.f);
    h2[(size_t)n * 128 + 64 + lane] = fmaxf(o1, 0.f);
  }
}

__device__ __forceinline__ int lower_bound(const int* __restrict__ a, int n, int key) {
  int lo = 0, hi = n;
  while (lo < hi) {
    int m = (lo + hi) >> 1;
    if (a[m] < key) lo = m + 1; else hi = m;
  }
  return lo;
}

// block per graph: mean-pool h2 over [start,end), then fc1(relu)+fc2 on wave 0.
__global__ void k_pool_fc(const float* __restrict__ h2, const int* __restrict__ batch,
                          const float* __restrict__ fc1W, const float* __restrict__ fc1b,
                          const float* __restrict__ fc2W, const float* __restrict__ fc2b,
                          float* __restrict__ out, int N, int G) {
  int g = blockIdx.x;
  __shared__ int bounds[2];
  if (threadIdx.x == 0) bounds[0] = lower_bound(batch, N, g);
  if (threadIdx.x == 1) bounds[1] = lower_bound(batch, N, g + 1);
  __syncthreads();
  int beg = bounds[0], end = bounds[1];
  int c = threadIdx.x & 127;
  int gr = threadIdx.x >> 7;  // 2 node-stride groups
  float acc = 0.f;
  for (int i = beg + gr; i < end; i += 2) acc += h2[(size_t)i * 128 + c];
  __shared__ float red[256];
  __shared__ float grow[128];
  red[threadIdx.x] = acc;
  __syncthreads();
  if (threadIdx.x < 128) {
    float s = red[threadIdx.x] + red[threadIdx.x + 128];
    int cnt = end - beg;
    grow[threadIdx.x] = s / (float)max(cnt, 1);
  }
  __syncthreads();
  if (threadIdx.x < 64) {
    int c1 = threadIdx.x;
    float o = fc1b[c1];
#pragma unroll 8
    for (int k = 0; k < 128; ++k) o = fmaf(grow[k], fc1W[k * 64 + c1], o);
    o = fmaxf(o, 0.f);
    float v = o * fc2W[c1];
#pragma unroll
    for (int off = 32; off; off >>= 1) v += __shfl_xor(v, off);
    if (c1 == 0) out[g] = v + fc2b[0];
  }
}

extern "C" void kernel_launch(void* const* d_in, const int* in_sizes, int n_in,
                              void* d_out, int out_size, void* d_ws, size_t ws_size,
                              hipStream_t stream) {
  const float* x = (const float*)d_in[0];
  const int* ei = (const int*)d_in[1];
  const int* batch = (const int*)d_in[2];
  const float* W1 = (const float*)d_in[3];
  const float* b1 = (const float*)d_in[4];
  const float* W2 = (const float*)d_in[5];
  const float* b2 = (const float*)d_in[6];
  const float* fc1W = (const float*)d_in[7];
  const float* fc1b = (const float*)d_in[8];
  const float* fc2W = (const float*)d_in[9];
  const float* fc2b = (const float*)d_in[10];
  float* out = (float*)d_out;

  int N = in_sizes[0] / 4;   // 100000
  int E = in_sizes[1] / 2;   // 1600000
  int G = out_size;          // 1024
  const int* src = ei;
  const int* dst = ei + E;

  char* ws = (char*)d_ws;
  size_t off = 0;
  auto take = [&](size_t b) {
    char* p = ws + off;
    off += (b + 255) & ~(size_t)255;
    return p;
  };
  int nb = (N + SCB - 1) / SCB;  // 98
  int* deg      = (int*)take((size_t)N * 4);
  int* row_ptr  = (int*)take((size_t)(N + 1) * 4);
  int* cursor   = (int*)take((size_t)N * 4);
  int* bsum     = (int*)take((size_t)(nb + 1) * 4);
  float* dinv   = (float*)take((size_t)N * 4);
  float* xp     = (float*)take((size_t)N * 4 * 4);
  int* csr_src  = (int*)take((size_t)E * 4);
  float* h1p    = (float*)take((size_t)N * 64 * 4);
  float* h2     = (float*)take((size_t)N * 128 * 4);
  (void)ws_size;

  hipMemsetAsync(deg, 0, (size_t)N * 4, stream);
  k_count_deg<<<(E + 255) / 256, 256, 0, stream>>>(dst, E, deg);
  k_prep<<<(N + 255) / 256, 256, 0, stream>>>(deg, x, dinv, xp, N);
  k_bsum<<<nb, 256, 0, stream>>>(deg, bsum, N);
  k_scan_b<<<1, 1024, 0, stream>>>(bsum, nb);
  k_rowptr<<<nb, 256, 0, stream>>>(deg, bsum, row_ptr, cursor, N);
  k_fill<<<(E + 255) / 256, 256, 0, stream>>>(src, dst, E, cursor, csr_src);
  k_conv1<<<4096, 256, 0, stream>>>(xp, row_ptr, csr_src, dinv, W1, b1, h1p, N);
  k_conv2<<<1024, 512, 0, stream>>>(h1p, row_ptr, csr_src, dinv, W2, b2, h2, N);
  k_pool_fc<<<G, 256, 0, stream>>>(h2, batch, fc1W, fc1b, fc2W, fc2b, out, N, G);
}